// Round 8
// baseline (329.879 us; speedup 1.0000x reference)
//
#include <hip/hip_runtime.h>
#include <hip/hip_bf16.h>

// ZorroPP — factorized form:
//   accrow[c] = exp(-t/64)*rowsum_sketch[c] + 0.01*rowsum_noise[c]
//   mu[c]     = g[c]/M * ( accrow[c] + (1/t)*g[c]*colsum_x[c]*len(h) )
//   out       = s*(x@W) - s*(mu@W) + b      (mu@W is a [K] GEMV!)
// so the [B,K] GEMM is over RAW x and W. x and W are pre-split hi/lo bf16
// once (exact, lo*lo dropped => ~2^-16 rel), making the GEMM inner loop
// pure LDS-staging + 12 MFMA (no f2bf VALU work).

#define SPLITK 8

typedef float f32x4 __attribute__((ext_vector_type(4)));
typedef short bf16x8 __attribute__((ext_vector_type(8)));

__device__ __forceinline__ short f2bf(float f) {
    unsigned u = __float_as_uint(f);
    unsigned r = (u + 0x7FFFu + ((u >> 16) & 1u)) >> 16;   // RNE
    return (short)r;
}
__device__ __forceinline__ float bf2f(short b) {
    return __uint_as_float(((unsigned)(unsigned short)b) << 16);
}

// flat split: src[8i..8i+7] f32 -> hi/lo bf16x8 (exact residual split)
__global__ __launch_bounds__(256) void split_kernel(const float* __restrict__ src,
                                                    short* __restrict__ hi,
                                                    short* __restrict__ lo) {
    int i = blockIdx.x * 256 + threadIdx.x;
    const f32x4* p = reinterpret_cast<const f32x4*>(src) + 2 * (size_t)i;
    f32x4 a = p[0];
    f32x4 b = p[1];
    float v[8] = {a.x, a.y, a.z, a.w, b.x, b.y, b.z, b.w};
    bf16x8 h, l;
#pragma unroll
    for (int j = 0; j < 8; ++j) {
        short hh = f2bf(v[j]);
        h[j] = hh;
        l[j] = f2bf(v[j] - bf2f(hh));
    }
    reinterpret_cast<bf16x8*>(hi)[i] = h;
    reinterpret_cast<bf16x8*>(lo)[i] = l;
}

// colsum[c] = sum_b x[b,c]; grid (C/256, B/8), 8 batched loads per thread
__global__ __launch_bounds__(256) void colsum_kernel(const float* __restrict__ x,
                                                     float* __restrict__ colsum,
                                                     int Cdim) {
    int c = blockIdx.x * 256 + threadIdx.x;
    const float* p = x + (size_t)(blockIdx.y * 8) * Cdim + c;
    float r0 = p[0 * (size_t)Cdim];
    float r1 = p[1 * (size_t)Cdim];
    float r2 = p[2 * (size_t)Cdim];
    float r3 = p[3 * (size_t)Cdim];
    float r4 = p[4 * (size_t)Cdim];
    float r5 = p[5 * (size_t)Cdim];
    float r6 = p[6 * (size_t)Cdim];
    float r7 = p[7 * (size_t)Cdim];
    __builtin_amdgcn_sched_barrier(0);
    float acc = ((r0 + r1) + (r2 + r3)) + ((r4 + r5) + (r6 + r7));
    atomicAdd(&colsum[c], acc);
}

// grid (C, 2): y==0 -> sketch (weight exp(-t/64)), y==1 -> noise (0.01).
// atomicAdd into accrow[row].
__global__ __launch_bounds__(256, 4) void rowsum_kernel(const float* __restrict__ sk,
                                                        const float* __restrict__ noise,
                                                        const int* __restrict__ t_ptr,
                                                        float* __restrict__ accrow,
                                                        int Msk) {
    int row = blockIdx.x;
    int tid = threadIdx.x;
    const float* src = (blockIdx.y == 0) ? sk : noise;
    const f32x4* p = reinterpret_cast<const f32x4*>(src + (size_t)row * Msk);
    int n4 = Msk >> 2;

    float sum = 0.0f;
    int base = 0;
    for (; base + 2048 <= n4; base += 2048) {
        const f32x4* q = p + base + tid;
        f32x4 a0 = __builtin_nontemporal_load(q + 0 * 256);
        f32x4 a1 = __builtin_nontemporal_load(q + 1 * 256);
        f32x4 a2 = __builtin_nontemporal_load(q + 2 * 256);
        f32x4 a3 = __builtin_nontemporal_load(q + 3 * 256);
        f32x4 a4 = __builtin_nontemporal_load(q + 4 * 256);
        f32x4 a5 = __builtin_nontemporal_load(q + 5 * 256);
        f32x4 a6 = __builtin_nontemporal_load(q + 6 * 256);
        f32x4 a7 = __builtin_nontemporal_load(q + 7 * 256);
        __builtin_amdgcn_sched_barrier(0);
        float s0 = (a0.x + a0.y) + (a0.z + a0.w);
        float s1 = (a1.x + a1.y) + (a1.z + a1.w);
        float s2 = (a2.x + a2.y) + (a2.z + a2.w);
        float s3 = (a3.x + a3.y) + (a3.z + a3.w);
        float s4 = (a4.x + a4.y) + (a4.z + a4.w);
        float s5 = (a5.x + a5.y) + (a5.z + a5.w);
        float s6 = (a6.x + a6.y) + (a6.z + a6.w);
        float s7 = (a7.x + a7.y) + (a7.z + a7.w);
        sum += ((s0 + s1) + (s2 + s3)) + ((s4 + s5) + (s6 + s7));
    }
    for (int i = base + tid; i < n4; i += 256) {
        f32x4 v = p[i];
        sum += (v.x + v.y) + (v.z + v.w);
    }

#pragma unroll
    for (int off = 32; off > 0; off >>= 1)
        sum += __shfl_down(sum, off);

    __shared__ float red[4];
    int wid = tid >> 6;
    if ((tid & 63) == 0) red[wid] = sum;
    __syncthreads();
    if (tid == 0) {
        float total = (red[0] + red[1]) + (red[2] + red[3]);
        float w;
        if (blockIdx.y == 0) {
            float t = (float)(*t_ptr);
            w = __expf(-t / 64.0f);
        } else {
            w = 0.01f;
        }
        atomicAdd(&accrow[row], w * total);
    }
}

// v[k] = sum_c mu[c]*W[c,k], mu computed inline from accrow/colsum.
// grid (ceil(K/64), 32): block handles 64 k-cols x 128 c-rows.
__global__ __launch_bounds__(256) void gemv_kernel(const float* __restrict__ W,
                                                   const float* __restrict__ accrow,
                                                   const float* __restrict__ colsum,
                                                   const float* __restrict__ g,
                                                   const int* __restrict__ t_ptr,
                                                   float* __restrict__ v,
                                                   int Cdim, int Kdim, int Msk,
                                                   float hcount) {
    int tid = threadIdx.x;
    int lane = tid & 63;
    int w = tid >> 6;
    int k = blockIdx.x * 64 + lane;
    bool kok = k < Kdim;
    int cbase = blockIdx.y * 128 + w * 32;

    float t = (float)(*t_ptr);
    float kap_h = hcount / t;
    float invM = 1.0f / (float)Msk;

    float sum = 0.0f;
    for (int c = cbase; c < cbase + 32; ++c) {
        float gc = g[c];
        float mu_c = gc * invM * (accrow[c] + kap_h * gc * colsum[c]);
        float wv = kok ? W[(size_t)c * Kdim + k] : 0.0f;
        sum += mu_c * wv;
    }

    __shared__ float part[4][64];
    part[w][lane] = sum;
    __syncthreads();
    if (w == 0 && kok) {
        float total = (part[0][lane] + part[1][lane]) +
                      (part[2][lane] + part[3][lane]);
        atomicAdd(&v[k], total);
    }
}

// atomic-fallback path only: out[i,k] = bias[k] - s*v[k]
__global__ __launch_bounds__(256) void init_out_kernel(const float* __restrict__ bias,
                                                       const float* __restrict__ v,
                                                       float* __restrict__ out,
                                                       int Kdim, int total, float s) {
    int i = blockIdx.x * 256 + threadIdx.x;
    if (i < total) {
        int k = i % Kdim;
        out[i] = bias[k] - s * v[k];
    }
}

// x @ W over the z-th C-chunk, operands pre-split hi/lo bf16.
// grid (B/64, ceil(K/64), SPLITK), 256 thr = 4 waves, each a 32x32 quadrant
// via 2x2 mfma_f32_16x16x32_bf16 frags x 3 passes (hh, hl, lh).
template <bool ATOMIC>
__global__ __launch_bounds__(256, 4) void gemm_kernel(const short* __restrict__ xhi,
                                                      const short* __restrict__ xlo,
                                                      const short* __restrict__ whi,
                                                      const short* __restrict__ wlo,
                                                      float* __restrict__ outp,
                                                      int Bdim, int Cdim, int Kdim,
                                                      int Kc, float s) {
    // [hi/lo][row][k], 40-elem rows: 80 B stride (b128-aligned, 20-bank step)
    __shared__ short As[2][64][40];
    __shared__ short Bs[2][64][40];

    const int tid = threadIdx.x;
    const int lane = tid & 63;
    const int w = tid >> 6;
    const int wr = w >> 1;
    const int wc = w & 1;
    const int row0 = blockIdx.x * 64;
    const int col0 = blockIdx.y * 64;
    const int cbeg = blockIdx.z * Kc;

    // A staging: thread -> (m, 8 consecutive k) as one bf16x8 per operand
    const int am = tid >> 2;
    const int ac8 = (tid & 3) * 8;
    // B staging: thread -> (n, 8 consecutive k), 16 coalesced ushort loads
    const int bn = tid & 63;
    const int bk8 = (tid >> 6) * 8;
    const int bcol = col0 + bn;
    const bool bok = bcol < Kdim;

    const int fr = lane & 15;
    const int fk8 = (lane >> 4) * 8;

    f32x4 acc[2][2] = {};

    for (int it = 0; it < Kc; it += 32) {
        const int c0 = cbeg + it;
        // ---- global loads (no conversion needed) ----
        const size_t aoff = (size_t)(row0 + am) * Cdim + c0 + ac8;
        bf16x8 ah = *reinterpret_cast<const bf16x8*>(&xhi[aoff]);
        bf16x8 al = *reinterpret_cast<const bf16x8*>(&xlo[aoff]);
        short bh[8], bl[8];
#pragma unroll
        for (int j = 0; j < 8; ++j) {
            size_t woff = (size_t)(c0 + bk8 + j) * Kdim + bcol;
            bh[j] = bok ? whi[woff] : (short)0;
            bl[j] = bok ? wlo[woff] : (short)0;
        }

        __syncthreads();   // previous iteration's frag reads done

        *reinterpret_cast<bf16x8*>(&As[0][am][ac8]) = ah;
        *reinterpret_cast<bf16x8*>(&As[1][am][ac8]) = al;
        bf16x8 bhv, blv;
#pragma unroll
        for (int j = 0; j < 8; ++j) { bhv[j] = bh[j]; blv[j] = bl[j]; }
        *reinterpret_cast<bf16x8*>(&Bs[0][bn][bk8]) = bhv;
        *reinterpret_cast<bf16x8*>(&Bs[1][bn][bk8]) = blv;

        __syncthreads();

        // ---- fragment reads (8x ds_read_b128) ----
        bf16x8 afr[2][2], bfr[2][2];
#pragma unroll
        for (int h = 0; h < 2; ++h) {
#pragma unroll
            for (int f = 0; f < 2; ++f) {
                afr[h][f] = *reinterpret_cast<const bf16x8*>(
                    &As[h][wr * 32 + f * 16 + fr][fk8]);
                bfr[h][f] = *reinterpret_cast<const bf16x8*>(
                    &Bs[h][wc * 32 + f * 16 + fr][fk8]);
            }
        }

        // ---- 12 MFMA: hh + hl + lh ----
#pragma unroll
        for (int mf = 0; mf < 2; ++mf) {
#pragma unroll
            for (int nf = 0; nf < 2; ++nf) {
                acc[mf][nf] = __builtin_amdgcn_mfma_f32_16x16x32_bf16(
                    afr[0][mf], bfr[0][nf], acc[mf][nf], 0, 0, 0);
                acc[mf][nf] = __builtin_amdgcn_mfma_f32_16x16x32_bf16(
                    afr[0][mf], bfr[1][nf], acc[mf][nf], 0, 0, 0);
                acc[mf][nf] = __builtin_amdgcn_mfma_f32_16x16x32_bf16(
                    afr[1][mf], bfr[0][nf], acc[mf][nf], 0, 0, 0);
            }
        }
    }

    // ---- epilogue: C/D layout col=lane&15, row=(lane>>4)*4+reg ----
#pragma unroll
    for (int mf = 0; mf < 2; ++mf) {
#pragma unroll
        for (int nf = 0; nf < 2; ++nf) {
#pragma unroll
            for (int r = 0; r < 4; ++r) {
                int row = row0 + wr * 32 + mf * 16 + (lane >> 4) * 4 + r;
                int col = col0 + wc * 32 + nf * 16 + (lane & 15);
                if (col < Kdim) {
                    if (ATOMIC)
                        atomicAdd(&outp[(size_t)row * Kdim + col],
                                  s * acc[mf][nf][r]);
                    else
                        outp[((size_t)blockIdx.z * Bdim + row) * Kdim + col] =
                            acc[mf][nf][r];
                }
            }
        }
    }
}

// out = s*(sum_z part - v[k]) + bias[k]; flat float4 over B*K
__global__ __launch_bounds__(256) void reduce_kernel(const float* __restrict__ part,
                                                     const float* __restrict__ bias,
                                                     const float* __restrict__ v,
                                                     float* __restrict__ out,
                                                     int total4, int Kdim, int perz,
                                                     float s) {
    int i = blockIdx.x * 256 + threadIdx.x;
    if (i >= total4) return;
    const float4* p4 = reinterpret_cast<const float4*>(part);
    float4 sum = p4[i];
#pragma unroll
    for (int z = 1; z < SPLITK; ++z) {
        float4 vv = p4[(size_t)z * (perz >> 2) + i];
        sum.x += vv.x; sum.y += vv.y; sum.z += vv.z; sum.w += vv.w;
    }
    int e = i * 4;
    int k0 = (e + 0) % Kdim, k1 = (e + 1) % Kdim;
    int k2 = (e + 2) % Kdim, k3 = (e + 3) % Kdim;
    float4 o;
    o.x = s * (sum.x - v[k0]) + bias[k0];
    o.y = s * (sum.y - v[k1]) + bias[k1];
    o.z = s * (sum.z - v[k2]) + bias[k2];
    o.w = s * (sum.w - v[k3]) + bias[k3];
    reinterpret_cast<float4*>(out)[i] = o;
}

extern "C" void kernel_launch(void* const* d_in, const int* in_sizes, int n_in,
                              void* d_out, int out_size, void* d_ws, size_t ws_size,
                              hipStream_t stream) {
    const float* x      = (const float*)d_in[0];   // [B, C]
    const float* sk     = (const float*)d_in[1];   // [C, M]
    const float* g      = (const float*)d_in[2];   // [C]
    const float* noise  = (const float*)d_in[3];   // [C, M]
    const float* W      = (const float*)d_in[4];   // [C, K]
    const float* bias   = (const float*)d_in[5];   // [K]
    // d_in[6] = h: only its LENGTH matters (sum of bincount == len(h))
    const int* t_ptr    = (const int*)d_in[7];

    int C    = in_sizes[2];
    int Bdim = in_sizes[0] / C;
    int Msk  = in_sizes[1] / C;
    int Kdim = in_sizes[5];
    float hcount = (float)in_sizes[6];

    // ws layout (floats): [colsum C][accrow C][v 1024] then 16B-aligned:
    // xhi, xlo (B*C shorts each), whi, wlo (C*K shorts each), part
    float* colsum = (float*)d_ws;
    float* accrow = colsum + C;
    float* v      = accrow + C;
    char* base    = (char*)(v + 1024);
    size_t xcnt = (size_t)Bdim * C;
    size_t wcnt = (size_t)C * Kdim;
    short* xhi = (short*)base;
    short* xlo = xhi + xcnt;
    short* whi = xlo + xcnt;
    short* wlo = whi + wcnt;
    float* part = (float*)(wlo + wcnt);

    size_t need = (size_t)((char*)(part + (size_t)SPLITK * Bdim * Kdim) - (char*)d_ws);
    bool use_partial = ws_size >= need;

    float s = (float)(1.0 / ((1.0 + 1e-6) * sqrt(0.375 + 1e-6)));
    int Kc = C / SPLITK;

    // 1) zero colsum+accrow+v (single memset)
    hipMemsetAsync(colsum, 0, (2 * C + 1024) * sizeof(float), stream);
    // 2) pre-split x and W into hi/lo bf16 (exact residual split)
    split_kernel<<<(int)(xcnt / 8 / 256), 256, 0, stream>>>(x, xhi, xlo);
    split_kernel<<<(int)(wcnt / 8 / 256), 256, 0, stream>>>(W, whi, wlo);
    // 3) colsum of x
    {
        dim3 grid(C / 256, Bdim / 8);
        colsum_kernel<<<grid, 256, 0, stream>>>(x, colsum, C);
    }
    // 4) weighted rowsums of sketch+noise -> accrow
    {
        dim3 grid(C, 2);
        rowsum_kernel<<<grid, 256, 0, stream>>>(sk, noise, t_ptr, accrow, Msk);
    }
    // 5) GEMM on pre-split operands (no mu dependency)
    dim3 ggrid(Bdim / 64, (Kdim + 63) / 64, SPLITK);
    // 6) GEMV v = mu @ W (mu computed inline)
    dim3 vgrid((Kdim + 63) / 64, 32);
    if (use_partial) {
        gemm_kernel<false><<<ggrid, 256, 0, stream>>>(xhi, xlo, whi, wlo, part,
                                                      Bdim, C, Kdim, Kc, s);
        gemv_kernel<<<vgrid, 256, 0, stream>>>(W, accrow, colsum, g, t_ptr, v,
                                               C, Kdim, Msk, hcount);
        int perz = Bdim * Kdim;
        int total4 = perz / 4;
        reduce_kernel<<<(total4 + 255) / 256, 256, 0, stream>>>(part, bias, v,
                                                                (float*)d_out,
                                                                total4, Kdim, perz, s);
    } else {
        gemv_kernel<<<vgrid, 256, 0, stream>>>(W, accrow, colsum, g, t_ptr, v,
                                               C, Kdim, Msk, hcount);
        int total = Bdim * Kdim;
        init_out_kernel<<<(total + 255) / 256, 256, 0, stream>>>(bias, v,
                                                                 (float*)d_out,
                                                                 Kdim, total, s);
        gemm_kernel<true><<<ggrid, 256, 0, stream>>>(xhi, xlo, whi, wlo,
                                                     (float*)d_out, Bdim, C, Kdim,
                                                     Kc, s);
    }
}